// Round 1
// baseline (6499.636 us; speedup 1.0000x reference)
//
#include <hip/hip_runtime.h>
#include <hip/hip_bf16.h>
#include <stdint.h>

typedef unsigned long long u64;

#define V_   32000
#define D_   512
#define H_   512
#define B_   8
#define T_   512
#define BT_  4096
#define G4H_ 2048

// =====================================================================
// Generic 128x128-tile fp32 GEMM:  C = act(A @ B^T + bias)
//   MODE 0: A = emb_W[src[m]],   B=W_ih (2048x512),  bias=b_ih+b_hh, N=2048,K=512
//   MODE 1: A = hs,              B=attn1_W(512x512), bias=attn1_b, tanh, N=512,K=512
//   MODE 2: A = [ctx | hs],      B=concat_W(512x1024),bias=concat_b,tanh, N=512,K=1024
//   MODE 3: A = comb,            B=emb_W(32000x512), bias=dec_b,   N=32000,K=512
// 256 threads, 8x8 micro-tile, BK=16, LDS pad 132 (2-way max => free).
// =====================================================================
template<int MODE>
__global__ __launch_bounds__(256)
void gemm128(const float* __restrict__ A1, const float* __restrict__ A2,
             const float* __restrict__ Bm, const float* __restrict__ bias,
             const float* __restrict__ bias2, const int* __restrict__ src,
             float* __restrict__ C, int M, int N, int K)
{
  __shared__ float As[16][132];
  __shared__ float Bs[16][132];
  const int tid = threadIdx.x;
  const int bm = blockIdx.y * 128, bn = blockIdx.x * 128;
  const int tx = tid & 15, ty = tid >> 4;
  const int lr = tid >> 2, lk4 = tid & 3;   // loader: row 0..63, k-float4 0..3

  int ga0 = 0, ga1 = 0;
  if constexpr (MODE == 0) { ga0 = src[bm + lr]; ga1 = src[bm + lr + 64]; }

  float acc[8][8];
  #pragma unroll
  for (int i = 0; i < 8; ++i)
    #pragma unroll
    for (int j = 0; j < 8; ++j) acc[i][j] = 0.f;

  for (int k0 = 0; k0 < K; k0 += 16) {
    const int ak = k0 + 4 * lk4;
    float4 av0, av1, bv0, bv1;
    if constexpr (MODE == 0) {
      av0 = *(const float4*)&A1[(long)ga0 * 512 + ak];
      av1 = *(const float4*)&A1[(long)ga1 * 512 + ak];
    } else if constexpr (MODE == 2) {
      if (ak < 512) {
        av0 = *(const float4*)&A1[(long)(bm + lr) * 512 + ak];
        av1 = *(const float4*)&A1[(long)(bm + lr + 64) * 512 + ak];
      } else {
        av0 = *(const float4*)&A2[(long)(bm + lr) * 512 + (ak - 512)];
        av1 = *(const float4*)&A2[(long)(bm + lr + 64) * 512 + (ak - 512)];
      }
    } else {
      av0 = *(const float4*)&A1[(long)(bm + lr) * K + ak];
      av1 = *(const float4*)&A1[(long)(bm + lr + 64) * K + ak];
    }
    bv0 = *(const float4*)&Bm[(long)(bn + lr) * K + ak];
    bv1 = *(const float4*)&Bm[(long)(bn + lr + 64) * K + ak];

    __syncthreads();
    As[4*lk4+0][lr]    = av0.x; As[4*lk4+1][lr]    = av0.y;
    As[4*lk4+2][lr]    = av0.z; As[4*lk4+3][lr]    = av0.w;
    As[4*lk4+0][lr+64] = av1.x; As[4*lk4+1][lr+64] = av1.y;
    As[4*lk4+2][lr+64] = av1.z; As[4*lk4+3][lr+64] = av1.w;
    Bs[4*lk4+0][lr]    = bv0.x; Bs[4*lk4+1][lr]    = bv0.y;
    Bs[4*lk4+2][lr]    = bv0.z; Bs[4*lk4+3][lr]    = bv0.w;
    Bs[4*lk4+0][lr+64] = bv1.x; Bs[4*lk4+1][lr+64] = bv1.y;
    Bs[4*lk4+2][lr+64] = bv1.z; Bs[4*lk4+3][lr+64] = bv1.w;
    __syncthreads();

    #pragma unroll
    for (int kk = 0; kk < 16; ++kk) {
      float4 a0 = *(float4*)&As[kk][ty * 8];
      float4 a1 = *(float4*)&As[kk][ty * 8 + 4];
      float4 b0 = *(float4*)&Bs[kk][tx * 4];
      float4 b1 = *(float4*)&Bs[kk][64 + tx * 4];
      float a[8] = {a0.x, a0.y, a0.z, a0.w, a1.x, a1.y, a1.z, a1.w};
      float b[8] = {b0.x, b0.y, b0.z, b0.w, b1.x, b1.y, b1.z, b1.w};
      #pragma unroll
      for (int i = 0; i < 8; ++i)
        #pragma unroll
        for (int j = 0; j < 8; ++j) acc[i][j] += a[i] * b[j];
    }
  }

  #pragma unroll
  for (int i = 0; i < 8; ++i) {
    const int m = bm + ty * 8 + i;
    #pragma unroll
    for (int half = 0; half < 2; ++half) {
      const int n0 = bn + half * 64 + tx * 4;
      float4 v;
      float* vv = (float*)&v;
      #pragma unroll
      for (int j = 0; j < 4; ++j) {
        float x = acc[i][half * 4 + j];
        x += bias[n0 + j];
        if constexpr (MODE == 0) x += bias2[n0 + j];
        if constexpr (MODE == 1 || MODE == 2) x = tanhf(x);
        vv[j] = x;
      }
      *(float4*)&C[(long)m * N + n0] = v;
    }
  }
}

// =====================================================================
// Persistent LSTM. 128 WGs x 256 thr. WG k owns h-dims [4k,4k+4) (all 4
// gates). W_hh slice in registers (32 f/thread). Per step:
//  ph1: partial dots (LDS h broadcast reads, conflict-free)
//  ph2: reduce 16 chunks + A contribution -> raw gates
//  ph3: 32 threads: gate math, c in regs, h -> hs + tagged 8B atomic bcast
//  ph4: spin on tagged hbuf -> h_lds for next step
// =====================================================================
__global__ __launch_bounds__(256)
void lstm_kernel(const float* __restrict__ A, const float* __restrict__ W_hh,
                 float* __restrict__ hs, u64* __restrict__ hbuf)
{
  __shared__ float h_lds[B_ * H_];      // 16 KB, [b][c]
  __shared__ float partial[16 * 129];   // [r][q*8+b], stride 129
  __shared__ float gvals[16 * 9];       // [r][b], pad 9
  const int tid = threadIdx.x;
  const int wg = blockIdx.x;
  const int d0 = wg * 4;
  const int r = tid & 15, q = tid >> 4;
  const int row_g = (r >> 2) * 512 + d0 + (r & 3);

  float4 w4[8];
  #pragma unroll
  for (int i = 0; i < 8; ++i)
    w4[i] = *(const float4*)&W_hh[(long)row_g * H_ + 4 * (q + 16 * i)];

  for (int s = tid; s < B_ * H_; s += 256) h_lds[s] = 0.f;

  const int r2 = tid >> 3, b2 = tid & 7;                        // tid<128
  const int arow = (tid < 128) ? ((r2 >> 2) * 512 + d0 + (r2 & 3)) : 0;
  const int d3 = (tid >> 3) & 3, b3 = tid & 7;                  // tid<32
  float c_reg = 0.f;
  __syncthreads();

  for (int t = 0; t < T_; ++t) {
    float a_val = 0.f;
    if (tid < 128) a_val = A[((long)b2 * T_ + t) * G4H_ + arow];

    // phase 1: partial dots
    float pacc[8] = {0, 0, 0, 0, 0, 0, 0, 0};
    #pragma unroll
    for (int i = 0; i < 8; ++i) {
      const int j4 = q + 16 * i;
      #pragma unroll
      for (int b = 0; b < 8; ++b) {
        float4 hv = *(float4*)&h_lds[b * H_ + 4 * j4];
        pacc[b] += w4[i].x * hv.x + w4[i].y * hv.y + w4[i].z * hv.z + w4[i].w * hv.w;
      }
    }
    #pragma unroll
    for (int b = 0; b < 8; ++b) partial[r * 129 + q * 8 + b] = pacc[b];
    __syncthreads();

    // phase 2: reduce + input-gate contribution
    if (tid < 128) {
      float g = a_val;
      #pragma unroll
      for (int qq = 0; qq < 16; ++qq) g += partial[r2 * 129 + qq * 8 + b2];
      gvals[r2 * 9 + b2] = g;
    }
    __syncthreads();

    // phase 3: gate nonlinearity + state update + broadcast
    if (tid < 32) {
      float gi = gvals[(0 + d3) * 9 + b3];
      float gf = gvals[(4 + d3) * 9 + b3];
      float gg = gvals[(8 + d3) * 9 + b3];
      float go = gvals[(12 + d3) * 9 + b3];
      float si = 1.f / (1.f + expf(-gi));
      float sf = 1.f / (1.f + expf(-gf));
      float so = 1.f / (1.f + expf(-go));
      c_reg = sf * c_reg + si * tanhf(gg);
      float hval = so * tanhf(c_reg);
      hs[((long)b3 * T_ + t) * H_ + d0 + d3] = hval;
      u64 pkt = ((u64)(unsigned)(t + 1) << 32) | (u64)__float_as_uint(hval);
      __hip_atomic_store(&hbuf[b3 * H_ + d0 + d3], pkt, __ATOMIC_RELAXED,
                         __HIP_MEMORY_SCOPE_AGENT);
    }

    // phase 4: gather new h from all WGs (tagged spin; data IS the flag)
    if (t < T_ - 1) {
      unsigned pend = 0xFFFFu;
      const int base = tid * 16;
      while (pend) {
        #pragma unroll
        for (int i = 0; i < 16; ++i) {
          if (pend & (1u << i)) {
            u64 u = __hip_atomic_load(&hbuf[base + i], __ATOMIC_RELAXED,
                                      __HIP_MEMORY_SCOPE_AGENT);
            if ((unsigned)(u >> 32) == (unsigned)(t + 1)) {
              h_lds[base + i] = __uint_as_float((unsigned)u);
              pend &= ~(1u << i);
            }
          }
        }
      }
    }
    __syncthreads();
  }
}

// ===================== s = tanh(h@W1^T+b1) . w2 + b2 =====================
__global__ __launch_bounds__(256)
void score_kernel(const float* __restrict__ S1, const float* __restrict__ w2,
                  const float* __restrict__ b2, float* __restrict__ scores)
{
  const int lane = threadIdx.x & 63;
  const int row = blockIdx.x * 4 + (threadIdx.x >> 6);
  const float4 a0 = *(const float4*)&S1[(long)row * 512 + lane * 4];
  const float4 a1 = *(const float4*)&S1[(long)row * 512 + 256 + lane * 4];
  const float4 w0 = *(const float4*)&w2[lane * 4];
  const float4 w1 = *(const float4*)&w2[256 + lane * 4];
  float s = a0.x * w0.x + a0.y * w0.y + a0.z * w0.z + a0.w * w0.w
          + a1.x * w1.x + a1.y * w1.y + a1.z * w1.z + a1.w * w1.w;
  #pragma unroll
  for (int off = 32; off; off >>= 1) s += __shfl_xor(s, off);
  if (lane == 0) scores[row] = s + b2[0];
}

// ============= softmax (global max) + cumulative context =============
__global__ __launch_bounds__(256)
void attn_ctx_kernel(const float* __restrict__ scores,
                     const float* __restrict__ hs, float* __restrict__ ctx)
{
  __shared__ float e_lds[T_];
  __shared__ float dinv_lds[T_];
  __shared__ float red[4];
  const int b = blockIdx.x, tid = threadIdx.x;
  float s0 = scores[b * T_ + tid];
  float s1 = scores[b * T_ + 256 + tid];
  float m = fmaxf(s0, s1);
  #pragma unroll
  for (int off = 32; off; off >>= 1) m = fmaxf(m, __shfl_xor(m, off));
  if ((tid & 63) == 0) red[tid >> 6] = m;
  __syncthreads();
  m = fmaxf(fmaxf(red[0], red[1]), fmaxf(red[2], red[3]));
  e_lds[tid] = expf(s0 - m);
  e_lds[tid + 256] = expf(s1 - m);
  __syncthreads();
  if (tid == 0) {
    float run = 0.f;
    for (int t = 0; t < T_; ++t) { run += e_lds[t]; dinv_lds[t] = 1.f / run; }
  }
  __syncthreads();

  float acc0 = 0.f, acc1 = 0.f;
  for (int t0 = 0; t0 < T_; t0 += 8) {
    float hv0[8], hv1[8];
    #pragma unroll
    for (int u = 0; u < 8; ++u) {
      const float* hp = &hs[((long)b * T_ + t0 + u) * H_];
      hv0[u] = hp[tid];
      hv1[u] = hp[tid + 256];
    }
    #pragma unroll
    for (int u = 0; u < 8; ++u) {
      float e = e_lds[t0 + u], di = dinv_lds[t0 + u];
      acc0 += e * hv0[u];
      acc1 += e * hv1[u];
      float* cp = &ctx[((long)b * T_ + t0 + u) * H_];
      cp[tid] = acc0 * di;
      cp[tid + 256] = acc1 * di;
    }
  }
}

// =====================================================================
extern "C" void kernel_launch(void* const* d_in, const int* in_sizes, int n_in,
                              void* d_out, int out_size, void* d_ws, size_t ws_size,
                              hipStream_t stream)
{
  const int*   src      = (const int*)  d_in[0];
  const float* emb_W    = (const float*)d_in[1];
  const float* W_ih     = (const float*)d_in[2];
  const float* W_hh     = (const float*)d_in[3];
  const float* b_ih     = (const float*)d_in[4];
  const float* b_hh     = (const float*)d_in[5];
  const float* attn1_W  = (const float*)d_in[6];
  const float* attn1_b  = (const float*)d_in[7];
  const float* attn2_W  = (const float*)d_in[8];
  const float* attn2_b  = (const float*)d_in[9];
  const float* concat_W = (const float*)d_in[10];
  const float* concat_b = (const float*)d_in[11];
  const float* dec_b    = (const float*)d_in[12];
  float* out = (float*)d_out;

  // workspace layout (~42 MB):
  //  [0, 33.5MB)  A_gates [4096][2048]; after LSTM reused as S1/ctx/comb
  //  [33.5, 41.9) hs [4096][512]
  //  then scores (16KB), hbuf (32KB)
  char* ws = (char*)d_ws;
  float* A_gates = (float*)(ws);
  float* S1      = (float*)(ws);
  float* ctx     = (float*)(ws + (size_t)8388608);
  float* comb    = (float*)(ws + (size_t)16777216);
  float* hs      = (float*)(ws + (size_t)33554432);
  float* scores  = (float*)(ws + (size_t)33554432 + 8388608);
  u64*   hbuf    = (u64*)  (ws + (size_t)33554432 + 8388608 + 16384);

  dim3 blk(256);
  // 1) gates input part: A = emb[src] @ W_ih^T + b_ih + b_hh
  gemm128<0><<<dim3(G4H_ / 128, BT_ / 128), blk, 0, stream>>>(
      emb_W, nullptr, W_ih, b_ih, b_hh, src, A_gates, BT_, G4H_, 512);
  // 2) clear tag buffer, then persistent LSTM
  hipMemsetAsync(hbuf, 0, (size_t)B_ * H_ * sizeof(u64), stream);
  lstm_kernel<<<dim3(128), blk, 0, stream>>>(A_gates, W_hh, hs, hbuf);
  // 3) S1 = tanh(hs @ attn1_W^T + b1)
  gemm128<1><<<dim3(512 / 128, BT_ / 128), blk, 0, stream>>>(
      hs, nullptr, attn1_W, attn1_b, nullptr, nullptr, S1, BT_, 512, 512);
  // 4) scores
  score_kernel<<<dim3(BT_ / 4), blk, 0, stream>>>(S1, attn2_W, attn2_b, scores);
  // 5) softmax-cumsum context
  attn_ctx_kernel<<<dim3(B_), blk, 0, stream>>>(scores, hs, ctx);
  // 6) comb = tanh([ctx|hs] @ concat_W^T + bc)
  gemm128<2><<<dim3(512 / 128, BT_ / 128), blk, 0, stream>>>(
      ctx, hs, concat_W, concat_b, nullptr, nullptr, comb, BT_, 512, 1024);
  // 7) logits = comb @ emb_W^T + dec_b
  gemm128<3><<<dim3(V_ / 128, BT_ / 128), blk, 0, stream>>>(
      comb, nullptr, emb_W, dec_b, nullptr, nullptr, out, BT_, V_, 512);
}